// Round 12
// baseline (298.130 us; speedup 1.0000x reference)
//
#include <hip/hip_runtime.h>
#include <hip/hip_bf16.h>

typedef __hip_bfloat16 bf16;
typedef __attribute__((ext_vector_type(8))) short short8;   // 8 bf16 (4 VGPRs)
typedef __attribute__((ext_vector_type(4))) short short4v;
typedef __attribute__((ext_vector_type(4))) float f32x4;

__device__ __forceinline__ short f2bf(float f) {            // f32 -> bf16 bits
    bf16 h = __float2bfloat16(f);
    return *reinterpret_cast<short*>(&h);
}
__device__ __forceinline__ float u2f(unsigned short u) {    // bf16 bits -> f32
    return __uint_as_float(((unsigned)u) << 16);
}
__device__ __forceinline__ unsigned cvt_pk(float lo, float hi) {
    unsigned r;                                             // 2xf32 -> 2xbf16
    asm("v_cvt_pk_bf16_f32 %0, %1, %2" : "=v"(r) : "v"(lo), "v"(hi));
    return r;
}

// Shapes: B=256, C=384, N=196 (14x14), N2=49 (7x7), HEADS=8, KD=16, D=64,
// NHKD=128, DH=512, OUT=384. Inputs fp32, output fp32.
// ws carve (143,654,912 B):
//   xT   bf16 [256][208][384]            @ 0
//   qinT bf16 [256][64][384] (alias attT)@ 40,894,464
//   attT bf16 [256][64][512]             @ 40,894,464  (rows p>=49 unused)
//   q_t  bf16 [256*8][49][16]            @ 57,671,680
//   kbf  bf16 [256*8][208][16] (packed)  @ 60,882,944
//   vT   bf16 [256*8][64][208]           @ 88,145,920
//   wkv  bf16 [768][384] (k,v,qproj w)   @ 142,671,872
//   pwb  bf16 [384][512]                 @ 143,261,696

// ---------------------------------------------------------------------------
// k_prep: blocks 0..1535  = {x chunk -> LDS fp32 (f32x4 coalesced, once);
//                            emit xT bf16 transpose (short8 stores); compute
//                            q_local dwconv + pool -> qinT bf16}
//         blocks 1536..3455 = weight cvt to bf16.
__global__ __launch_bounds__(256) void k_prep(const float* __restrict__ x,
        const float* __restrict__ qlw, const float* __restrict__ qlb,
        const float* __restrict__ kw, const float* __restrict__ vw,
        const float* __restrict__ qpw, const float* __restrict__ pw,
        short* __restrict__ xT, short* __restrict__ qinT,
        short* __restrict__ wkv, short* __restrict__ pwb) {
    __shared__ float sX[64 * 197];           // 50,432 B, stride 197 (coprime)
    int bid = blockIdx.x, tid = threadIdx.x;
    if (bid < 1536) {
        int ct = bid % 6, b = bid / 6;
        // ---- load x[b][ct*64..+64][0..195] as f32x4, coalesced, once
        const float* xb = x + ((long)b * 384 + ct * 64) * 196;
        for (int i = tid; i < 64 * 49; i += 256) {
            int c = i / 49, n4 = i % 49;
            f32x4 v = *(const f32x4*)(xb + c * 196 + n4 * 4);
            float* d = sX + c * 197 + n4 * 4;
            d[0] = v[0]; d[1] = v[1]; d[2] = v[2]; d[3] = v[3];
        }
        __syncthreads();
        // ---- xT[b][n][c] = bf16(x[b][c][n]); short8 stores; rows 196..207 zero
        for (int i = tid; i < 196 * 8; i += 256) {
            int n = i >> 3, c0 = (i & 7) * 8;
            short8 o;
#pragma unroll
            for (int j = 0; j < 8; j++) o[j] = f2bf(sX[(c0 + j) * 197 + n]);
            *(short8*)(xT + ((long)b * 208 + n) * 384 + ct * 64 + c0) = o;
        }
        for (int i = tid; i < 12 * 8; i += 256) {
            int n = 196 + (i >> 3), c0 = (i & 7) * 8;
            *(short8*)(xT + ((long)b * 208 + n) * 384 + ct * 64 + c0)
                = (short8){0,0,0,0,0,0,0,0};
        }
        // ---- qinT: thread owns column c = tid%64; p walks tid/64, +4
        {
            int c = tid & 63;
            int cg = ct * 64 + c;
            const float* wc = qlw + cg * 9;
            float w9[9];
#pragma unroll
            for (int j = 0; j < 9; j++) w9[j] = wc[j];
            float bia = qlb[cg];
            const float* xr = sX + c * 197;
            for (int p = tid >> 6; p < 49; p += 4) {
                int h2 = p / 7, w2 = p % 7;
                float acc = bia;
#pragma unroll
                for (int kh = 0; kh < 3; kh++) {
                    int hin = 2 * h2 - 1 + kh;
                    if (hin < 0 || hin >= 14) continue;
#pragma unroll
                    for (int kk = 0; kk < 3; kk++) {
                        int win = 2 * w2 - 1 + kk;
                        if (win < 0 || win >= 14) continue;
                        acc += xr[hin * 14 + win] * w9[kh * 3 + kk];
                    }
                }
                acc += xr[(2 * h2) * 14 + 2 * w2];
                qinT[((long)b * 64 + p) * 384 + cg] = f2bf(acc);
            }
            for (int p = 49 + (tid >> 6); p < 64; p += 4)
                qinT[((long)b * 64 + p) * 384 + cg] = 0;
        }
    } else {
        // ---- weights -> bf16: wkv = [kw | vw | qpw], pwb = pw
        int idx = (bid - 1536) * 256 + tid;
        if (idx < 294912) {
            float v;
            if (idx < 49152) v = kw[idx];
            else if (idx < 245760) v = vw[idx - 49152];
            else v = qpw[idx - 245760];
            wkv[idx] = f2bf(v);
        } else {
            int j = idx - 294912;
            pwb[j] = f2bf(pw[j]);
        }
    }
}

// ---------------------------------------------------------------------------
// K+V+Q 1x1 convs via MFMA, XCD-grouped decode (11 sub-blocks of one b share
// the XCD L2). BK=64, 6 K-iterations, sA/sB LDS-staged with reg-prefetch
// (round-9 form: best measured 52.4us). Wave = 2 octiles x 7 ntiles.
// kbf PACKED [bh][208][16].
__global__ __launch_bounds__(256, 3) void k_kv_mfma(const short* __restrict__ wkv,
        const short* __restrict__ xT, const short* __restrict__ qinT,
        const float* __restrict__ kb, const float* __restrict__ kbs,
        const float* __restrict__ kbb, const float* __restrict__ vb,
        const float* __restrict__ vbs, const float* __restrict__ vbb,
        const float* __restrict__ qpb, const float* __restrict__ qbs,
        const float* __restrict__ qbb,
        short* __restrict__ kbf, short* __restrict__ vT, short* __restrict__ q_t) {
    __shared__ short sA[128 * 72];       // w: [oc][k64]
    __shared__ short sB[112 * 72];       // x: [n-half][k64]
    int bid = blockIdx.x, tid = threadIdx.x;
    int tt = bid >> 3;
    int b = (bid & 7) * 32 + tt / 11;    // 2816 = 8 XCD * 32 b * 11 sub
    int sub = tt % 11;
    int wave = tid >> 6, lane = tid & 63, quad = lane >> 4, l15 = lane & 15;

    if (sub == 10) {
        // ---------------- Q projection: [128 oc] x [64 p] over K=384, BK=64
        f32x4 qa[2][4];
#pragma unroll
        for (int t = 0; t < 2; t++)
#pragma unroll
            for (int nt = 0; nt < 4; nt++) qa[t][nt] = (f32x4){0.f,0.f,0.f,0.f};
        for (int ct = 0; ct < 6; ct++) {
#pragma unroll
            for (int j = 0; j < 4; j++) {
                int s = tid + j * 256, r = s >> 3, c8 = s & 7;
                *(short8*)(sA + r * 72 + c8 * 8)
                    = *(const short8*)(wkv + (long)(640 + r) * 384 + ct * 64 + c8 * 8);
            }
#pragma unroll
            for (int j = 0; j < 2; j++) {
                int s = tid + j * 256, r = s >> 3, c8 = s & 7;
                *(short8*)(sB + r * 72 + c8 * 8)
                    = *(const short8*)(qinT + ((long)b * 64 + r) * 384 + ct * 64 + c8 * 8);
            }
            __syncthreads();
#pragma unroll
            for (int ks = 0; ks < 2; ks++) {
                short8 bw0 = *(const short8*)(sA + (wave * 32 + l15) * 72 + ks * 32 + quad * 8);
                short8 bw1 = *(const short8*)(sA + (wave * 32 + 16 + l15) * 72 + ks * 32 + quad * 8);
#pragma unroll
                for (int nt = 0; nt < 4; nt++) {
                    short8 ax = *(const short8*)(sB + (nt * 16 + l15) * 72 + ks * 32 + quad * 8);
                    qa[0][nt] = __builtin_amdgcn_mfma_f32_16x16x32_bf16(ax, bw0, qa[0][nt], 0, 0, 0);
                    qa[1][nt] = __builtin_amdgcn_mfma_f32_16x16x32_bf16(ax, bw1, qa[1][nt], 0, 0, 0);
                }
            }
            __syncthreads();
        }
#pragma unroll
        for (int t = 0; t < 2; t++) {
            int oc = wave * 32 + t * 16 + l15;          // 0..127
            int hh = oc >> 4, kd = oc & 15;
            float sc = qbs[oc], bi = qpb[oc], bb2 = qbb[oc];
#pragma unroll
            for (int nt = 0; nt < 4; nt++) {
#pragma unroll
                for (int r = 0; r < 4; r++) {
                    int p = nt * 16 + quad * 4 + r;
                    if (p < 49)
                        q_t[(((long)b * 8 + hh) * 49 + p) * 16 + kd]
                            = f2bf(sc * (qa[t][nt][r] + bi) + bb2);
                }
            }
        }
        return;
    }

    // ---------------- K/V path: block 128oc x 112n; wave = 2 octiles x 7 nt
    int ocblk = sub >> 1;                // 0..4
    int nh = sub & 1;                    // n-half: rows [nh*112, +112)
    int ocbase = ocblk * 128;
    int nbase = nh * 112;
    int nrows = nh ? 96 : 112;           // real xT rows in this half
    int obase = wave * 32;               // wave's oc offset within block

    f32x4 acc[2][7];
#pragma unroll
    for (int oct = 0; oct < 2; oct++)
#pragma unroll
        for (int j = 0; j < 7; j++) acc[oct][j] = (f32x4){0.f,0.f,0.f,0.f};

    // one-time zero of sB rows 96..111 for the short half (never re-written)
    if (nh) {
        for (int i = tid; i < 128; i += 256) {
            int row = 96 + (i >> 3), c8 = i & 7;
            *(short8*)(sB + row * 72 + c8 * 8) = (short8){0,0,0,0,0,0,0,0};
        }
    }

    short8 pA[4], pB[4], nA[4], nB[4];
    {
#pragma unroll
        for (int j = 0; j < 4; j++) {
            int s = tid + j * 256, r = s >> 3, c8 = s & 7;
            pA[j] = *(const short8*)(wkv + (long)(ocbase + r) * 384 + c8 * 8);
            if (s < nrows * 8)
                pB[j] = *(const short8*)(xT + ((long)b * 208 + nbase + r) * 384 + c8 * 8);
        }
    }

    for (int ct = 0; ct < 6; ct++) {
#pragma unroll
        for (int j = 0; j < 4; j++) {
            int s = tid + j * 256, r = s >> 3, c8 = s & 7;
            *(short8*)(sA + r * 72 + c8 * 8) = pA[j];
            if (s < nrows * 8)
                *(short8*)(sB + r * 72 + c8 * 8) = pB[j];
        }
        __syncthreads();
        if (ct < 5) {
            int cn = ct + 1;
#pragma unroll
            for (int j = 0; j < 4; j++) {
                int s = tid + j * 256, r = s >> 3, c8 = s & 7;
                nA[j] = *(const short8*)(wkv + (long)(ocbase + r) * 384 + cn * 64 + c8 * 8);
                if (s < nrows * 8)
                    nB[j] = *(const short8*)(xT + ((long)b * 208 + nbase + r) * 384 + cn * 64 + c8 * 8);
            }
        }
#pragma unroll
        for (int ks = 0; ks < 2; ks++) {
            short8 aw0 = *(const short8*)(sA + (obase + l15) * 72 + ks * 32 + quad * 8);
            short8 aw1 = *(const short8*)(sA + (obase + 16 + l15) * 72 + ks * 32 + quad * 8);
#pragma unroll
            for (int j = 0; j < 7; j++) {
                short8 bx = *(const short8*)(sB + (j * 16 + l15) * 72 + ks * 32 + quad * 8);
                acc[0][j] = __builtin_amdgcn_mfma_f32_16x16x32_bf16(bx, aw0, acc[0][j], 0, 0, 0);
                acc[1][j] = __builtin_amdgcn_mfma_f32_16x16x32_bf16(bx, aw1, acc[1][j], 0, 0, 0);
            }
        }
        __syncthreads();
#pragma unroll
        for (int j = 0; j < 4; j++) { pA[j] = nA[j]; pB[j] = nB[j]; }
    }

    // epilogue: row (quad*4+r) = n-within-tile, col (l15) = oc within octile
#pragma unroll
    for (int oct = 0; oct < 2; oct++) {
        int oc = ocbase + obase + oct * 16 + l15;
        if (ocblk == 0) {                             // K outputs, packed 16-kd
            int hh = oc >> 4, kd = oc & 15;
            float sc = kbs[oc], bi = kb[oc], bb2 = kbb[oc];
            short* kbase = kbf + ((long)(b * 8 + hh) * 208) * 16 + kd;
#pragma unroll
            for (int j = 0; j < 7; j++) {
                int nt = nh * 7 + j;
                if (nt >= 13) break;
                int n0 = nt * 16 + quad * 4;
#pragma unroll
                for (int r = 0; r < 4; r++)
                    kbase[(long)(n0 + r) * 16] = f2bf(sc * (acc[oct][j][r] + bi) + bb2);
            }
        } else {                                      // V outputs
            int cc = oc - 128, hh = cc >> 6, d = cc & 63;
            float sc = vbs[cc], bi = vb[cc], bb2 = vbb[cc];
            short* vbase = vT + ((long)(b * 8 + hh) * 64 + d) * 208;
#pragma unroll
            for (int j = 0; j < 7; j++) {
                int nt = nh * 7 + j;
                if (nt >= 13) break;
                int n0 = nt * 16 + quad * 4;
                short4v ov;
                ov.x = f2bf(sc * (acc[oct][j][0] + bi) + bb2);
                ov.y = f2bf(sc * (acc[oct][j][1] + bi) + bb2);
                ov.z = f2bf(sc * (acc[oct][j][2] + bi) + bb2);
                ov.w = f2bf(sc * (acc[oct][j][3] + bi) + bb2);
                *(short4v*)(vbase + n0) = ov;
            }
        }
    }
}

// ---------------------------------------------------------------------------
// attention per (b,h), swapped-operand QK^T with bias as MFMA C-in and Q
// pre-scaled by 0.25 (exact in bf16). PV: P packed via v_cvt_pk_bf16_f32
// (2 inst per short4v, was ~12) and transposed through sP[64][136] in TWO
// 4-ks batches (2 LDS write->read stall chains instead of 7). LDS 47.1KB —
// still 3 blocks/CU (regs cap at 3 anyway). attT rows p>=49 not written.
__global__ __launch_bounds__(256, 3) void k_attn(const short* __restrict__ q_t,
        const short* __restrict__ kbf, const short* __restrict__ vT,
        const float* __restrict__ bias_tab,
        const float* __restrict__ vlw, const float* __restrict__ vlb,
        const float* __restrict__ vlbs, const float* __restrict__ vlbb,
        short* __restrict__ attT) {
    __shared__ short smem[23552];            // 47,104 B
    short* sQ = smem;                        // [64][40] phase A (cols 16+ zero)
    short* sK = smem + 2560;                 // [208][24] phase A
    short* sV = smem;                        // [64][232] phase B (alias A)
    short* sP = smem + 14848;                // [64][136] P batch tile
    int bh = blockIdx.x, b = bh >> 3, h = bh & 7, tid = threadIdx.x;
    int wave = tid >> 6, lane = tid & 63, quad = lane >> 4, l15 = lane & 15;
    int prow = wave * 16 + l15;

    // ---- issue Q, K, bias loads (all independent)
    const short8* qg8 = (const short8*)(q_t + (long)bh * 784);
    short8 qv[2]; int qp[2], qc[2];
#pragma unroll
    for (int j = 0; j < 2; j++) {
        int i = tid + j * 256;
        qp[j] = i / 5; qc[j] = i % 5;
        qv[j] = (short8){0,0,0,0,0,0,0,0};
        if (i < 320 && qp[j] < 49 && qc[j] < 2) {
            short8 t = qg8[qp[j] * 2 + qc[j]];
#pragma unroll
            for (int jj = 0; jj < 8; jj++)           // x0.25: exact exp shift
                qv[j][jj] = f2bf(u2f((unsigned short)t[jj]) * 0.25f);
        }
    }
    const short8* kg8 = (const short8*)(kbf + (long)bh * 3328);
    short8 kv[2];
#pragma unroll
    for (int j = 0; j < 2; j++) {
        int i = tid + j * 256;
        if (i < 416) kv[j] = kg8[i];
    }
    int pb = prow < 49 ? prow : 48;
    const float* bp = bias_tab + ((long)(h * 49 + pb) * 196 + quad * 4);
    f32x4 bi[13];
#pragma unroll
    for (int nt = 0; nt < 13; nt++) bi[nt] = *(const f32x4*)(bp + nt * 16);

    // ---- stage Q, K
#pragma unroll
    for (int j = 0; j < 2; j++) {
        int i = tid + j * 256;
        if (i < 320) *(short8*)(sQ + qp[j] * 40 + qc[j] * 8) = qv[j];
    }
#pragma unroll
    for (int j = 0; j < 2; j++) {
        int i = tid + j * 256;
        if (i < 416) *(short8*)(sK + (i >> 1) * 24 + (i & 1) * 8) = kv[j];
    }
    __syncthreads();

    // ---- QK^T swapped, C-in = bias: lane holds S[p=prow][n=nt*16+quad*4+r]
    f32x4 s2[13];
    short8 aQ = *(const short8*)(sQ + prow * 40 + quad * 8);
#pragma unroll
    for (int nt = 0; nt < 13; nt++) {
        short8 bK = (short8){0,0,0,0,0,0,0,0};
        if (quad < 2) bK = *(const short8*)(sK + (nt * 16 + l15) * 24 + quad * 8);
        s2[nt] = __builtin_amdgcn_mfma_f32_16x16x32_bf16(bK, aQ, bi[nt], 0, 0, 0);
    }
    __syncthreads();        // sQ/sK dead; region becomes sV

    // ---- mask n>=196 (nt=12, quad*4+r >= 4)
#pragma unroll
    for (int r = 0; r < 4; r++)
        if (quad * 4 + r >= 4) s2[12][r] = -1e30f;

    // ---- issue V loads (land during softmax)
    const short* vg = vT + (long)bh * 13312;
    short8 vv[7]; int vd[7], vc[7];
#pragma unroll
    for (int j = 0; j < 7; j++) {
        int i = tid + j * 256;
        vd[j] = i / 26; vc[j] = i % 26;
        if (i < 1664) vv[j] = *(const short8*)(vg + i * 8);
    }

    // ---- softmax over the lane-resident row
    float m = -3e38f;
#pragma unroll
    for (int nt = 0; nt < 13; nt++)
        m = fmaxf(m, fmaxf(fmaxf(s2[nt][0], s2[nt][1]), fmaxf(s2[nt][2], s2[nt][3])));
    m = fmaxf(m, __shfl_xor(m, 16));
    m = fmaxf(m, __shfl_xor(m, 32));
    float sum = 0.f;
#pragma unroll
    for (int nt = 0; nt < 13; nt++) {
#pragma unroll
        for (int r = 0; r < 4; r++) {
            float e = __expf(s2[nt][r] - m);
            s2[nt][r] = e; sum += e;
        }
    }
    sum += __shfl_xor(sum, 16);
    sum += __shfl_xor(sum, 32);
    float inv = 1.f / sum;

    // ---- stage V (+ zero pad cols 208..223)
#pragma unroll
    for (int j = 0; j < 7; j++) {
        int i = tid + j * 256;
        if (i < 1664) *(short8*)(sV + vd[j] * 232 + vc[j] * 8) = vv[j];
    }
    {
        int d = tid >> 2, c0 = 208 + (tid & 3) * 4;
        *(short4v*)(sV + d * 232 + c0) = (short4v){0,0,0,0};
    }
    __syncthreads();        // sV visible to all waves

    // ---- PV: two 4-ks batches; P packed with cvt_pk, transposed via sP.
    //      sP stride 136 shorts = 272B (16B-aligned rows; bank-stride 4 ->
    //      2-way on b128 reads = free). Per-wave rows only; DS in-order per
    //      wave => no barriers. Batch 1 overwrites cols after batch 0 reads.
    f32x4 o[4];
#pragma unroll
    for (int dt = 0; dt < 4; dt++) o[dt] = (f32x4){0.f,0.f,0.f,0.f};
#pragma unroll
    for (int bb = 0; bb < 2; bb++) {
#pragma unroll
        for (int ntl = 0; ntl < 8; ntl++) {
            int nt = bb * 8 + ntl;
            if (nt > 13) break;
            uint2 w;
            if (nt < 13) {
                w.x = cvt_pk(s2[nt][0] * inv, s2[nt][1] * inv);
                w.y = cvt_pk(s2[nt][2] * inv, s2[nt][3] * inv);
            } else w = (uint2){0u, 0u};
            *(uint2*)(sP + prow * 136 + ntl * 16 + quad * 4) = w;
        }
#pragma unroll
        for (int ksl = 0; ksl < 4; ksl++) {
            int ks = bb * 4 + ksl;
            if (ks > 6) break;
            short8 aP = *(const short8*)(sP + prow * 136 + ksl * 32 + quad * 8);
#pragma unroll
            for (int dt = 0; dt < 4; dt++) {
                short8 bV = *(const short8*)(sV + (dt * 16 + l15) * 232 + ks * 32 + quad * 8);
                o[dt] = __builtin_amdgcn_mfma_f32_16x16x32_bf16(aP, bV, o[dt], 0, 0, 0);
            }
        }
    }

    // ---- epilogue: v_local 9-tap from sV + BN + ReLU -> attT (p<49 only)
#pragma unroll
    for (int r = 0; r < 4; r++) {
        int p = wave * 16 + quad * 4 + r;
        if (p >= 49) continue;
        int h2 = p / 7, w2 = p % 7;
#pragma unroll
        for (int dt = 0; dt < 4; dt++) {
            int d = dt * 16 + l15, c = h * 64 + d;
            float acc2 = vlb[c];
            const float* wc = vlw + c * 9;
            const short* vrow = sV + d * 232;
#pragma unroll
            for (int kh = 0; kh < 3; kh++) {
                int hin = 2 * h2 - 1 + kh;
                if (hin < 0 || hin >= 14) continue;
#pragma unroll
                for (int kk = 0; kk < 3; kk++) {
                    int win = 2 * w2 - 1 + kk;
                    if (win < 0 || win >= 14) continue;
                    acc2 += u2f((unsigned short)vrow[hin * 14 + win]) * wc[kh * 3 + kk];
                }
            }
            float vl = vlbs[c] * acc2 + vlbb[c];
            attT[((long)b * 64 + p) * 512 + h * 64 + d]
                = f2bf(fmaxf(o[dt][r] + vl, 0.f));
        }
    }
}

// ---------------------------------------------------------------------------
// out = bn(conv1x1(relu(att))) via MFMA. XCD-grouped decode: 3 ocblks of one
// b share the attT slab via the same XCD's L2. Pad rows 49..63 of sB zeroed
// once; per-ct staging covers rows 0..48 only.
__global__ __launch_bounds__(256, 4) void k_pconv_mfma(const short* __restrict__ attT,
        const short* __restrict__ pwb, const float* __restrict__ bias,
        const float* __restrict__ bns, const float* __restrict__ bnb,
        float* __restrict__ out) {
    __shared__ short sA[128 * 72];
    __shared__ short sB[64 * 72];
    int bid = blockIdx.x, tid = threadIdx.x;
    int tt = bid >> 3;
    int b = (bid & 7) * 32 + tt / 3;     // 768 = 8 XCD * 32 b * 3 ocblk
    int ocblk = tt % 3;
    int wave = tid >> 6, lane = tid & 63, quad = lane >> 4, l15 = lane & 15;
    int ocbase = ocblk * 128;

    // zero sB rows 49..63 once (static across all ct)
    for (int i = tid; i < 15 * 8; i += 256) {
        int r = 49 + i / 8, c8 = i % 8;
        *(short8*)(sB + r * 72 + c8 * 8) = (short8){0,0,0,0,0,0,0,0};
    }

    f32x4 acc[2][4];
#pragma unroll
    for (int t = 0; t < 2; t++)
#pragma unroll
        for (int nt = 0; nt < 4; nt++) acc[t][nt] = (f32x4){0.f,0.f,0.f,0.f};

    for (int ct = 0; ct < 8; ct++) {
        for (int i = tid; i < 1024; i += 256) {
            int r = i >> 3, c8 = i & 7;
            *(short8*)(sA + r * 72 + c8 * 8)
                = *(const short8*)(pwb + (long)(ocbase + r) * 512 + ct * 64 + c8 * 8);
        }
        for (int i = tid; i < 392; i += 256) {       // rows 0..48 only
            int r = i >> 3, c8 = i & 7;
            *(short8*)(sB + r * 72 + c8 * 8)
                = *(const short8*)(attT + ((long)b * 64 + r) * 512 + ct * 64 + c8 * 8);
        }
        __syncthreads();
        short8 a00 = *(const short8*)(sA + (wave * 32 + l15) * 72 + quad * 8);
        short8 a01 = *(const short8*)(sA + (wave * 32 + l15) * 72 + 32 + quad * 8);
        short8 a10 = *(const short8*)(sA + (wave * 32 + 16 + l15) * 72 + quad * 8);
        short8 a11 = *(const short8*)(sA + (wave * 32 + 16 + l15) * 72 + 32 + quad * 8);
#pragma unroll
        for (int nt = 0; nt < 4; nt++) {
            short8 b0 = *(const short8*)(sB + (nt * 16 + l15) * 72 + quad * 8);
            short8 b1 = *(const short8*)(sB + (nt * 16 + l15) * 72 + 32 + quad * 8);
            acc[0][nt] = __builtin_amdgcn_mfma_f32_16x16x32_bf16(a00, b0, acc[0][nt], 0, 0, 0);
            acc[0][nt] = __builtin_amdgcn_mfma_f32_16x16x32_bf16(a01, b1, acc[0][nt], 0, 0, 0);
            acc[1][nt] = __builtin_amdgcn_mfma_f32_16x16x32_bf16(a10, b0, acc[1][nt], 0, 0, 0);
            acc[1][nt] = __builtin_amdgcn_mfma_f32_16x16x32_bf16(a11, b1, acc[1][nt], 0, 0, 0);
        }
        __syncthreads();
    }

#pragma unroll
    for (int t = 0; t < 2; t++) {
#pragma unroll
        for (int nt = 0; nt < 4; nt++) {
            int p = nt * 16 + l15;
            if (p >= 49) continue;
#pragma unroll
            for (int r = 0; r < 4; r++) {
                int oc = ocbase + wave * 32 + t * 16 + quad * 4 + r;
                out[((long)b * 384 + oc) * 49 + p]
                    = bns[oc] * (acc[t][nt][r] + bias[oc]) + bnb[oc];
            }
        }
    }
}

// ---------------------------------------------------------------------------
extern "C" void kernel_launch(void* const* d_in, const int* in_sizes, int n_in,
                              void* d_out, int out_size, void* d_ws, size_t ws_size,
                              hipStream_t stream) {
    const float* x    = (const float*)d_in[0];
    const float* qlw  = (const float*)d_in[1];
    const float* qlb  = (const float*)d_in[2];
    const float* qpw  = (const float*)d_in[3];
    const float* qpb  = (const float*)d_in[4];
    const float* qbs  = (const float*)d_in[5];
    const float* qbb  = (const float*)d_in[6];
    const float* kw   = (const float*)d_in[7];
    const float* kb   = (const float*)d_in[8];
    const float* kbs  = (const float*)d_in[9];
    const float* kbb  = (const float*)d_in[10];
    const float* vw   = (const float*)d_in[11];
    const float* vb   = (const float*)d_in[12];
    const float* vbs  = (const float*)d_in[13];
    const float* vbb  = (const float*)d_in[14];
    const float* vlw  = (const float*)d_in[15];
    const float* vlb  = (const float*)d_in[16];
    const float* vlbs = (const float*)d_in[17];
    const float* vlbb = (const float*)d_in[18];
    const float* btab = (const float*)d_in[19];
    const float* pw   = (const float*)d_in[20];
    const float* pb   = (const float*)d_in[21];
    const float* pbs  = (const float*)d_in[22];
    const float* pbb  = (const float*)d_in[23];
    float* out = (float*)d_out;

    char* W = (char*)d_ws;
    short* xT   = (short*)(W + 0);
    short* qinT = (short*)(W + 40894464);     // aliased by attT
    short* attT = (short*)(W + 40894464);
    short* q_t  = (short*)(W + 57671680);
    short* kbf  = (short*)(W + 60882944);     // packed [2048][208][16]
    short* vT   = (short*)(W + 88145920);
    short* wkv  = (short*)(W + 142671872);
    short* pwb  = (short*)(W + 143261696);    // end 143,654,912
    if (ws_size < 143654912) return;

    k_prep      <<< 3456, 256, 0, stream>>>(x, qlw, qlb, kw, vw, qpw, pw,
                                            xT, qinT, wkv, pwb);
    k_kv_mfma   <<< 2816, 256, 0, stream>>>(wkv, xT, qinT,
                                            kb, kbs, kbb, vb, vbs, vbb,
                                            qpb, qbs, qbb, kbf, vT, q_t);
    k_attn      <<< 2048, 256, 0, stream>>>(q_t, kbf, vT, btab,
                                            vlw, vlb, vlbs, vlbb, attT);
    k_pconv_mfma<<<  768, 256, 0, stream>>>(attT, pwb, pb, pbs, pbb, out);
}

// Round 13
// 288.947 us; speedup vs baseline: 1.0318x; 1.0318x over previous
//
#include <hip/hip_runtime.h>
#include <hip/hip_bf16.h>

typedef __hip_bfloat16 bf16;
typedef __attribute__((ext_vector_type(8))) short short8;   // 8 bf16 (4 VGPRs)
typedef __attribute__((ext_vector_type(4))) short short4v;
typedef __attribute__((ext_vector_type(4))) float f32x4;

__device__ __forceinline__ short f2bf(float f) {            // f32 -> bf16 bits
    bf16 h = __float2bfloat16(f);
    return *reinterpret_cast<short*>(&h);
}
__device__ __forceinline__ float u2f(unsigned short u) {    // bf16 bits -> f32
    return __uint_as_float(((unsigned)u) << 16);
}
__device__ __forceinline__ unsigned cvt_pk(float lo, float hi) {
    unsigned r;                                             // 2xf32 -> 2xbf16
    asm("v_cvt_pk_bf16_f32 %0, %1, %2" : "=v"(r) : "v"(lo), "v"(hi));
    return r;
}

// Shapes: B=256, C=384, N=196 (14x14), N2=49 (7x7), HEADS=8, KD=16, D=64,
// NHKD=128, DH=512, OUT=384. Inputs fp32, output fp32.
// ws carve (143,654,912 B):
//   xT   bf16 [256][208][384]            @ 0
//   qinT bf16 [256][64][384] (alias attT)@ 40,894,464
//   attT bf16 [256][64][512]             @ 40,894,464  (rows p>=49 unused)
//   q_t  bf16 [256*8][49][16]            @ 57,671,680
//   kbf  bf16 [256*8][208][16] (packed)  @ 60,882,944
//   vT   bf16 [256*8][64][208]           @ 88,145,920
//   wkv  bf16 [768][384] (k,v,qproj w)   @ 142,671,872
//   pwb  bf16 [384][512]                 @ 143,261,696

// ---------------------------------------------------------------------------
// k_prep: blocks 0..1535  = {x chunk -> LDS fp32 (f32x4 coalesced, once);
//                            emit xT bf16 transpose (short8 stores); compute
//                            q_local dwconv + pool -> qinT bf16}
//         blocks 1536..3455 = weight cvt to bf16.
__global__ __launch_bounds__(256) void k_prep(const float* __restrict__ x,
        const float* __restrict__ qlw, const float* __restrict__ qlb,
        const float* __restrict__ kw, const float* __restrict__ vw,
        const float* __restrict__ qpw, const float* __restrict__ pw,
        short* __restrict__ xT, short* __restrict__ qinT,
        short* __restrict__ wkv, short* __restrict__ pwb) {
    __shared__ float sX[64 * 197];           // 50,432 B, stride 197 (coprime)
    int bid = blockIdx.x, tid = threadIdx.x;
    if (bid < 1536) {
        int ct = bid % 6, b = bid / 6;
        // ---- load x[b][ct*64..+64][0..195] as f32x4, coalesced, once
        const float* xb = x + ((long)b * 384 + ct * 64) * 196;
        for (int i = tid; i < 64 * 49; i += 256) {
            int c = i / 49, n4 = i % 49;
            f32x4 v = *(const f32x4*)(xb + c * 196 + n4 * 4);
            float* d = sX + c * 197 + n4 * 4;
            d[0] = v[0]; d[1] = v[1]; d[2] = v[2]; d[3] = v[3];
        }
        __syncthreads();
        // ---- xT[b][n][c] = bf16(x[b][c][n]); short8 stores; rows 196..207 zero
        for (int i = tid; i < 196 * 8; i += 256) {
            int n = i >> 3, c0 = (i & 7) * 8;
            short8 o;
#pragma unroll
            for (int j = 0; j < 8; j++) o[j] = f2bf(sX[(c0 + j) * 197 + n]);
            *(short8*)(xT + ((long)b * 208 + n) * 384 + ct * 64 + c0) = o;
        }
        for (int i = tid; i < 12 * 8; i += 256) {
            int n = 196 + (i >> 3), c0 = (i & 7) * 8;
            *(short8*)(xT + ((long)b * 208 + n) * 384 + ct * 64 + c0)
                = (short8){0,0,0,0,0,0,0,0};
        }
        // ---- qinT: thread owns column c = tid%64; p walks tid/64, +4
        {
            int c = tid & 63;
            int cg = ct * 64 + c;
            const float* wc = qlw + cg * 9;
            float w9[9];
#pragma unroll
            for (int j = 0; j < 9; j++) w9[j] = wc[j];
            float bia = qlb[cg];
            const float* xr = sX + c * 197;
            for (int p = tid >> 6; p < 49; p += 4) {
                int h2 = p / 7, w2 = p % 7;
                float acc = bia;
#pragma unroll
                for (int kh = 0; kh < 3; kh++) {
                    int hin = 2 * h2 - 1 + kh;
                    if (hin < 0 || hin >= 14) continue;
#pragma unroll
                    for (int kk = 0; kk < 3; kk++) {
                        int win = 2 * w2 - 1 + kk;
                        if (win < 0 || win >= 14) continue;
                        acc += xr[hin * 14 + win] * w9[kh * 3 + kk];
                    }
                }
                acc += xr[(2 * h2) * 14 + 2 * w2];
                qinT[((long)b * 64 + p) * 384 + cg] = f2bf(acc);
            }
            for (int p = 49 + (tid >> 6); p < 64; p += 4)
                qinT[((long)b * 64 + p) * 384 + cg] = 0;
        }
    } else {
        // ---- weights -> bf16: wkv = [kw | vw | qpw], pwb = pw
        int idx = (bid - 1536) * 256 + tid;
        if (idx < 294912) {
            float v;
            if (idx < 49152) v = kw[idx];
            else if (idx < 245760) v = vw[idx - 49152];
            else v = qpw[idx - 245760];
            wkv[idx] = f2bf(v);
        } else {
            int j = idx - 294912;
            pwb[j] = f2bf(pw[j]);
        }
    }
}

// ---------------------------------------------------------------------------
// K+V+Q 1x1 convs via MFMA, XCD-grouped decode (11 sub-blocks of one b share
// the XCD L2). BK=64, 6 K-iterations, sA/sB LDS-staged with reg-prefetch
// (round-9 form: best measured 52.4us). Wave = 2 octiles x 7 ntiles.
// kbf PACKED [bh][208][16].
__global__ __launch_bounds__(256, 3) void k_kv_mfma(const short* __restrict__ wkv,
        const short* __restrict__ xT, const short* __restrict__ qinT,
        const float* __restrict__ kb, const float* __restrict__ kbs,
        const float* __restrict__ kbb, const float* __restrict__ vb,
        const float* __restrict__ vbs, const float* __restrict__ vbb,
        const float* __restrict__ qpb, const float* __restrict__ qbs,
        const float* __restrict__ qbb,
        short* __restrict__ kbf, short* __restrict__ vT, short* __restrict__ q_t) {
    __shared__ short sA[128 * 72];       // w: [oc][k64]
    __shared__ short sB[112 * 72];       // x: [n-half][k64]
    int bid = blockIdx.x, tid = threadIdx.x;
    int tt = bid >> 3;
    int b = (bid & 7) * 32 + tt / 11;    // 2816 = 8 XCD * 32 b * 11 sub
    int sub = tt % 11;
    int wave = tid >> 6, lane = tid & 63, quad = lane >> 4, l15 = lane & 15;

    if (sub == 10) {
        // ---------------- Q projection: [128 oc] x [64 p] over K=384, BK=64
        f32x4 qa[2][4];
#pragma unroll
        for (int t = 0; t < 2; t++)
#pragma unroll
            for (int nt = 0; nt < 4; nt++) qa[t][nt] = (f32x4){0.f,0.f,0.f,0.f};
        for (int ct = 0; ct < 6; ct++) {
#pragma unroll
            for (int j = 0; j < 4; j++) {
                int s = tid + j * 256, r = s >> 3, c8 = s & 7;
                *(short8*)(sA + r * 72 + c8 * 8)
                    = *(const short8*)(wkv + (long)(640 + r) * 384 + ct * 64 + c8 * 8);
            }
#pragma unroll
            for (int j = 0; j < 2; j++) {
                int s = tid + j * 256, r = s >> 3, c8 = s & 7;
                *(short8*)(sB + r * 72 + c8 * 8)
                    = *(const short8*)(qinT + ((long)b * 64 + r) * 384 + ct * 64 + c8 * 8);
            }
            __syncthreads();
#pragma unroll
            for (int ks = 0; ks < 2; ks++) {
                short8 bw0 = *(const short8*)(sA + (wave * 32 + l15) * 72 + ks * 32 + quad * 8);
                short8 bw1 = *(const short8*)(sA + (wave * 32 + 16 + l15) * 72 + ks * 32 + quad * 8);
#pragma unroll
                for (int nt = 0; nt < 4; nt++) {
                    short8 ax = *(const short8*)(sB + (nt * 16 + l15) * 72 + ks * 32 + quad * 8);
                    qa[0][nt] = __builtin_amdgcn_mfma_f32_16x16x32_bf16(ax, bw0, qa[0][nt], 0, 0, 0);
                    qa[1][nt] = __builtin_amdgcn_mfma_f32_16x16x32_bf16(ax, bw1, qa[1][nt], 0, 0, 0);
                }
            }
            __syncthreads();
        }
#pragma unroll
        for (int t = 0; t < 2; t++) {
            int oc = wave * 32 + t * 16 + l15;          // 0..127
            int hh = oc >> 4, kd = oc & 15;
            float sc = qbs[oc], bi = qpb[oc], bb2 = qbb[oc];
#pragma unroll
            for (int nt = 0; nt < 4; nt++) {
#pragma unroll
                for (int r = 0; r < 4; r++) {
                    int p = nt * 16 + quad * 4 + r;
                    if (p < 49)
                        q_t[(((long)b * 8 + hh) * 49 + p) * 16 + kd]
                            = f2bf(sc * (qa[t][nt][r] + bi) + bb2);
                }
            }
        }
        return;
    }

    // ---------------- K/V path: block 128oc x 112n; wave = 2 octiles x 7 nt
    int ocblk = sub >> 1;                // 0..4
    int nh = sub & 1;                    // n-half: rows [nh*112, +112)
    int ocbase = ocblk * 128;
    int nbase = nh * 112;
    int nrows = nh ? 96 : 112;           // real xT rows in this half
    int obase = wave * 32;               // wave's oc offset within block

    f32x4 acc[2][7];
#pragma unroll
    for (int oct = 0; oct < 2; oct++)
#pragma unroll
        for (int j = 0; j < 7; j++) acc[oct][j] = (f32x4){0.f,0.f,0.f,0.f};

    // one-time zero of sB rows 96..111 for the short half (never re-written)
    if (nh) {
        for (int i = tid; i < 128; i += 256) {
            int row = 96 + (i >> 3), c8 = i & 7;
            *(short8*)(sB + row * 72 + c8 * 8) = (short8){0,0,0,0,0,0,0,0};
        }
    }

    short8 pA[4], pB[4], nA[4], nB[4];
    {
#pragma unroll
        for (int j = 0; j < 4; j++) {
            int s = tid + j * 256, r = s >> 3, c8 = s & 7;
            pA[j] = *(const short8*)(wkv + (long)(ocbase + r) * 384 + c8 * 8);
            if (s < nrows * 8)
                pB[j] = *(const short8*)(xT + ((long)b * 208 + nbase + r) * 384 + c8 * 8);
        }
    }

    for (int ct = 0; ct < 6; ct++) {
#pragma unroll
        for (int j = 0; j < 4; j++) {
            int s = tid + j * 256, r = s >> 3, c8 = s & 7;
            *(short8*)(sA + r * 72 + c8 * 8) = pA[j];
            if (s < nrows * 8)
                *(short8*)(sB + r * 72 + c8 * 8) = pB[j];
        }
        __syncthreads();
        if (ct < 5) {
            int cn = ct + 1;
#pragma unroll
            for (int j = 0; j < 4; j++) {
                int s = tid + j * 256, r = s >> 3, c8 = s & 7;
                nA[j] = *(const short8*)(wkv + (long)(ocbase + r) * 384 + cn * 64 + c8 * 8);
                if (s < nrows * 8)
                    nB[j] = *(const short8*)(xT + ((long)b * 208 + nbase + r) * 384 + cn * 64 + c8 * 8);
            }
        }
#pragma unroll
        for (int ks = 0; ks < 2; ks++) {
            short8 aw0 = *(const short8*)(sA + (obase + l15) * 72 + ks * 32 + quad * 8);
            short8 aw1 = *(const short8*)(sA + (obase + 16 + l15) * 72 + ks * 32 + quad * 8);
#pragma unroll
            for (int j = 0; j < 7; j++) {
                short8 bx = *(const short8*)(sB + (j * 16 + l15) * 72 + ks * 32 + quad * 8);
                acc[0][j] = __builtin_amdgcn_mfma_f32_16x16x32_bf16(bx, aw0, acc[0][j], 0, 0, 0);
                acc[1][j] = __builtin_amdgcn_mfma_f32_16x16x32_bf16(bx, aw1, acc[1][j], 0, 0, 0);
            }
        }
        __syncthreads();
#pragma unroll
        for (int j = 0; j < 4; j++) { pA[j] = nA[j]; pB[j] = nB[j]; }
    }

    // epilogue: row (quad*4+r) = n-within-tile, col (l15) = oc within octile
#pragma unroll
    for (int oct = 0; oct < 2; oct++) {
        int oc = ocbase + obase + oct * 16 + l15;
        if (ocblk == 0) {                             // K outputs, packed 16-kd
            int hh = oc >> 4, kd = oc & 15;
            float sc = kbs[oc], bi = kb[oc], bb2 = kbb[oc];
            short* kbase = kbf + ((long)(b * 8 + hh) * 208) * 16 + kd;
#pragma unroll
            for (int j = 0; j < 7; j++) {
                int nt = nh * 7 + j;
                if (nt >= 13) break;
                int n0 = nt * 16 + quad * 4;
#pragma unroll
                for (int r = 0; r < 4; r++)
                    kbase[(long)(n0 + r) * 16] = f2bf(sc * (acc[oct][j][r] + bi) + bb2);
            }
        } else {                                      // V outputs
            int cc = oc - 128, hh = cc >> 6, d = cc & 63;
            float sc = vbs[cc], bi = vb[cc], bb2 = vbb[cc];
            short* vbase = vT + ((long)(b * 8 + hh) * 64 + d) * 208;
#pragma unroll
            for (int j = 0; j < 7; j++) {
                int nt = nh * 7 + j;
                if (nt >= 13) break;
                int n0 = nt * 16 + quad * 4;
                short4v ov;
                ov.x = f2bf(sc * (acc[oct][j][0] + bi) + bb2);
                ov.y = f2bf(sc * (acc[oct][j][1] + bi) + bb2);
                ov.z = f2bf(sc * (acc[oct][j][2] + bi) + bb2);
                ov.w = f2bf(sc * (acc[oct][j][3] + bi) + bb2);
                *(short4v*)(vbase + n0) = ov;
            }
        }
    }
}

// ---------------------------------------------------------------------------
// attention per (b,h), swapped-operand QK^T with bias as MFMA C-in and Q
// pre-scaled by 0.25 (exact in bf16). PV: P packed via v_cvt_pk_bf16_f32,
// transposed through sP[64][72] in FOUR 2-ks batches. LDS total 38,912 B
// (sV 29,696 + sP 9,216) -> 3 blocks/CU under the ~128KB shareable pool
// (47.1KB cost a resident block in round 12). attT rows p>=49 not written.
__global__ __launch_bounds__(256, 3) void k_attn(const short* __restrict__ q_t,
        const short* __restrict__ kbf, const short* __restrict__ vT,
        const float* __restrict__ bias_tab,
        const float* __restrict__ vlw, const float* __restrict__ vlb,
        const float* __restrict__ vlbs, const float* __restrict__ vlbb,
        short* __restrict__ attT) {
    __shared__ short smem[19456];            // 38,912 B
    short* sQ = smem;                        // [64][40] phase A (cols 16+ zero)
    short* sK = smem + 2560;                 // [208][24] phase A
    short* sV = smem;                        // [64][232] phase B (alias A)
    short* sP = smem + 14848;                // [64][72] P batch tile
    int bh = blockIdx.x, b = bh >> 3, h = bh & 7, tid = threadIdx.x;
    int wave = tid >> 6, lane = tid & 63, quad = lane >> 4, l15 = lane & 15;
    int prow = wave * 16 + l15;

    // ---- issue Q, K, bias loads (all independent)
    const short8* qg8 = (const short8*)(q_t + (long)bh * 784);
    short8 qv[2]; int qp[2], qc[2];
#pragma unroll
    for (int j = 0; j < 2; j++) {
        int i = tid + j * 256;
        qp[j] = i / 5; qc[j] = i % 5;
        qv[j] = (short8){0,0,0,0,0,0,0,0};
        if (i < 320 && qp[j] < 49 && qc[j] < 2) {
            short8 t = qg8[qp[j] * 2 + qc[j]];
#pragma unroll
            for (int jj = 0; jj < 8; jj++)           // x0.25: exact exp shift
                qv[j][jj] = f2bf(u2f((unsigned short)t[jj]) * 0.25f);
        }
    }
    const short8* kg8 = (const short8*)(kbf + (long)bh * 3328);
    short8 kv[2];
#pragma unroll
    for (int j = 0; j < 2; j++) {
        int i = tid + j * 256;
        if (i < 416) kv[j] = kg8[i];
    }
    int pb = prow < 49 ? prow : 48;
    const float* bp = bias_tab + ((long)(h * 49 + pb) * 196 + quad * 4);
    f32x4 bi[13];
#pragma unroll
    for (int nt = 0; nt < 13; nt++) bi[nt] = *(const f32x4*)(bp + nt * 16);

    // ---- stage Q, K
#pragma unroll
    for (int j = 0; j < 2; j++) {
        int i = tid + j * 256;
        if (i < 320) *(short8*)(sQ + qp[j] * 40 + qc[j] * 8) = qv[j];
    }
#pragma unroll
    for (int j = 0; j < 2; j++) {
        int i = tid + j * 256;
        if (i < 416) *(short8*)(sK + (i >> 1) * 24 + (i & 1) * 8) = kv[j];
    }
    __syncthreads();

    // ---- QK^T swapped, C-in = bias: lane holds S[p=prow][n=nt*16+quad*4+r]
    f32x4 s2[13];
    short8 aQ = *(const short8*)(sQ + prow * 40 + quad * 8);
#pragma unroll
    for (int nt = 0; nt < 13; nt++) {
        short8 bK = (short8){0,0,0,0,0,0,0,0};
        if (quad < 2) bK = *(const short8*)(sK + (nt * 16 + l15) * 24 + quad * 8);
        s2[nt] = __builtin_amdgcn_mfma_f32_16x16x32_bf16(bK, aQ, bi[nt], 0, 0, 0);
    }
    __syncthreads();        // sQ/sK dead; region becomes sV

    // ---- mask n>=196 (nt=12, quad*4+r >= 4)
#pragma unroll
    for (int r = 0; r < 4; r++)
        if (quad * 4 + r >= 4) s2[12][r] = -1e30f;

    // ---- issue V loads (land during softmax)
    const short* vg = vT + (long)bh * 13312;
    short8 vv[7]; int vd[7], vc[7];
#pragma unroll
    for (int j = 0; j < 7; j++) {
        int i = tid + j * 256;
        vd[j] = i / 26; vc[j] = i % 26;
        if (i < 1664) vv[j] = *(const short8*)(vg + i * 8);
    }

    // ---- softmax over the lane-resident row
    float m = -3e38f;
#pragma unroll
    for (int nt = 0; nt < 13; nt++)
        m = fmaxf(m, fmaxf(fmaxf(s2[nt][0], s2[nt][1]), fmaxf(s2[nt][2], s2[nt][3])));
    m = fmaxf(m, __shfl_xor(m, 16));
    m = fmaxf(m, __shfl_xor(m, 32));
    float sum = 0.f;
#pragma unroll
    for (int nt = 0; nt < 13; nt++) {
#pragma unroll
        for (int r = 0; r < 4; r++) {
            float e = __expf(s2[nt][r] - m);
            s2[nt][r] = e; sum += e;
        }
    }
    sum += __shfl_xor(sum, 16);
    sum += __shfl_xor(sum, 32);
    float inv = 1.f / sum;

    // ---- stage V (+ zero pad cols 208..223)
#pragma unroll
    for (int j = 0; j < 7; j++) {
        int i = tid + j * 256;
        if (i < 1664) *(short8*)(sV + vd[j] * 232 + vc[j] * 8) = vv[j];
    }
    {
        int d = tid >> 2, c0 = 208 + (tid & 3) * 4;
        *(short4v*)(sV + d * 232 + c0) = (short4v){0,0,0,0};
    }
    __syncthreads();        // sV visible to all waves

    // ---- PV: four 2-ks batches; P packed with cvt_pk, transposed via sP.
    //      sP stride 72 shorts = 144B (bank-start 4*l15 -> 2-way = free).
    //      Per-wave rows only; DS in-order per wave => no barriers.
    f32x4 o[4];
#pragma unroll
    for (int dt = 0; dt < 4; dt++) o[dt] = (f32x4){0.f,0.f,0.f,0.f};
#pragma unroll
    for (int bb = 0; bb < 4; bb++) {
#pragma unroll
        for (int ntl = 0; ntl < 4; ntl++) {
            int nt = bb * 4 + ntl;
            uint2 w;
            if (nt < 13) {
                w.x = cvt_pk(s2[nt][0] * inv, s2[nt][1] * inv);
                w.y = cvt_pk(s2[nt][2] * inv, s2[nt][3] * inv);
            } else w = (uint2){0u, 0u};
            *(uint2*)(sP + prow * 72 + ntl * 16 + quad * 4) = w;
        }
#pragma unroll
        for (int ksl = 0; ksl < 2; ksl++) {
            int ks = bb * 2 + ksl;
            if (ks > 6) break;
            short8 aP = *(const short8*)(sP + prow * 72 + ksl * 32 + quad * 8);
#pragma unroll
            for (int dt = 0; dt < 4; dt++) {
                short8 bV = *(const short8*)(sV + (dt * 16 + l15) * 232 + ks * 32 + quad * 8);
                o[dt] = __builtin_amdgcn_mfma_f32_16x16x32_bf16(aP, bV, o[dt], 0, 0, 0);
            }
        }
    }

    // ---- epilogue: v_local 9-tap from sV + BN + ReLU -> attT (p<49 only)
#pragma unroll
    for (int r = 0; r < 4; r++) {
        int p = wave * 16 + quad * 4 + r;
        if (p >= 49) continue;
        int h2 = p / 7, w2 = p % 7;
#pragma unroll
        for (int dt = 0; dt < 4; dt++) {
            int d = dt * 16 + l15, c = h * 64 + d;
            float acc2 = vlb[c];
            const float* wc = vlw + c * 9;
            const short* vrow = sV + d * 232;
#pragma unroll
            for (int kh = 0; kh < 3; kh++) {
                int hin = 2 * h2 - 1 + kh;
                if (hin < 0 || hin >= 14) continue;
#pragma unroll
                for (int kk = 0; kk < 3; kk++) {
                    int win = 2 * w2 - 1 + kk;
                    if (win < 0 || win >= 14) continue;
                    acc2 += u2f((unsigned short)vrow[hin * 14 + win]) * wc[kh * 3 + kk];
                }
            }
            float vl = vlbs[c] * acc2 + vlbb[c];
            attT[((long)b * 64 + p) * 512 + h * 64 + d]
                = f2bf(fmaxf(o[dt][r] + vl, 0.f));
        }
    }
}

// ---------------------------------------------------------------------------
// out = bn(conv1x1(relu(att))) via MFMA. XCD-grouped decode: 3 ocblks of one
// b share the attT slab via the same XCD's L2. Pad rows 49..63 of sB zeroed
// once; per-ct staging covers rows 0..48 only.
__global__ __launch_bounds__(256, 4) void k_pconv_mfma(const short* __restrict__ attT,
        const short* __restrict__ pwb, const float* __restrict__ bias,
        const float* __restrict__ bns, const float* __restrict__ bnb,
        float* __restrict__ out) {
    __shared__ short sA[128 * 72];
    __shared__ short sB[64 * 72];
    int bid = blockIdx.x, tid = threadIdx.x;
    int tt = bid >> 3;
    int b = (bid & 7) * 32 + tt / 3;     // 768 = 8 XCD * 32 b * 3 ocblk
    int ocblk = tt % 3;
    int wave = tid >> 6, lane = tid & 63, quad = lane >> 4, l15 = lane & 15;
    int ocbase = ocblk * 128;

    // zero sB rows 49..63 once (static across all ct)
    for (int i = tid; i < 15 * 8; i += 256) {
        int r = 49 + i / 8, c8 = i % 8;
        *(short8*)(sB + r * 72 + c8 * 8) = (short8){0,0,0,0,0,0,0,0};
    }

    f32x4 acc[2][4];
#pragma unroll
    for (int t = 0; t < 2; t++)
#pragma unroll
        for (int nt = 0; nt < 4; nt++) acc[t][nt] = (f32x4){0.f,0.f,0.f,0.f};

    for (int ct = 0; ct < 8; ct++) {
        for (int i = tid; i < 1024; i += 256) {
            int r = i >> 3, c8 = i & 7;
            *(short8*)(sA + r * 72 + c8 * 8)
                = *(const short8*)(pwb + (long)(ocbase + r) * 512 + ct * 64 + c8 * 8);
        }
        for (int i = tid; i < 392; i += 256) {       // rows 0..48 only
            int r = i >> 3, c8 = i & 7;
            *(short8*)(sB + r * 72 + c8 * 8)
                = *(const short8*)(attT + ((long)b * 64 + r) * 512 + ct * 64 + c8 * 8);
        }
        __syncthreads();
        short8 a00 = *(const short8*)(sA + (wave * 32 + l15) * 72 + quad * 8);
        short8 a01 = *(const short8*)(sA + (wave * 32 + l15) * 72 + 32 + quad * 8);
        short8 a10 = *(const short8*)(sA + (wave * 32 + 16 + l15) * 72 + quad * 8);
        short8 a11 = *(const short8*)(sA + (wave * 32 + 16 + l15) * 72 + 32 + quad * 8);
#pragma unroll
        for (int nt = 0; nt < 4; nt++) {
            short8 b0 = *(const short8*)(sB + (nt * 16 + l15) * 72 + quad * 8);
            short8 b1 = *(const short8*)(sB + (nt * 16 + l15) * 72 + 32 + quad * 8);
            acc[0][nt] = __builtin_amdgcn_mfma_f32_16x16x32_bf16(a00, b0, acc[0][nt], 0, 0, 0);
            acc[0][nt] = __builtin_amdgcn_mfma_f32_16x16x32_bf16(a01, b1, acc[0][nt], 0, 0, 0);
            acc[1][nt] = __builtin_amdgcn_mfma_f32_16x16x32_bf16(a10, b0, acc[1][nt], 0, 0, 0);
            acc[1][nt] = __builtin_amdgcn_mfma_f32_16x16x32_bf16(a11, b1, acc[1][nt], 0, 0, 0);
        }
        __syncthreads();
    }

#pragma unroll
    for (int t = 0; t < 2; t++) {
#pragma unroll
        for (int nt = 0; nt < 4; nt++) {
            int p = nt * 16 + l15;
            if (p >= 49) continue;
#pragma unroll
            for (int r = 0; r < 4; r++) {
                int oc = ocbase + wave * 32 + t * 16 + quad * 4 + r;
                out[((long)b * 384 + oc) * 49 + p]
                    = bns[oc] * (acc[t][nt][r] + bias[oc]) + bnb[oc];
            }
        }
    }
}

// ---------------------------------------------------------------------------
extern "C" void kernel_launch(void* const* d_in, const int* in_sizes, int n_in,
                              void* d_out, int out_size, void* d_ws, size_t ws_size,
                              hipStream_t stream) {
    const float* x    = (const float*)d_in[0];
    const float* qlw  = (const float*)d_in[1];
    const float* qlb  = (const float*)d_in[2];
    const float* qpw  = (const float*)d_in[3];
    const float* qpb  = (const float*)d_in[4];
    const float* qbs  = (const float*)d_in[5];
    const float* qbb  = (const float*)d_in[6];
    const float* kw   = (const float*)d_in[7];
    const float* kb   = (const float*)d_in[8];
    const float* kbs  = (const float*)d_in[9];
    const float* kbb  = (const float*)d_in[10];
    const float* vw   = (const float*)d_in[11];
    const float* vb   = (const float*)d_in[12];
    const float* vbs  = (const float*)d_in[13];
    const float* vbb  = (const float*)d_in[14];
    const float* vlw  = (const float*)d_in[15];
    const float* vlb  = (const float*)d_in[16];
    const float* vlbs = (const float*)d_in[17];
    const float* vlbb = (const float*)d_in[18];
    const float* btab = (const float*)d_in[19];
    const float* pw   = (const float*)d_in[20];
    const float* pb   = (const float*)d_in[21];
    const float* pbs  = (const float*)d_in[22];
    const float* pbb  = (const float*)d_in[23];
    float* out = (float*)d_out;

    char* W = (char*)d_ws;
    short* xT   = (short*)(W + 0);
    short* qinT = (short*)(W + 40894464);     // aliased by attT
    short* attT = (short*)(W + 40894464);
    short* q_t  = (short*)(W + 57671680);
    short* kbf  = (short*)(W + 60882944);     // packed [2048][208][16]
    short* vT   = (short*)(W + 88145920);
    short* wkv  = (short*)(W + 142671872);
    short* pwb  = (short*)(W + 143261696);    // end 143,654,912
    if (ws_size < 143654912) return;

    k_prep      <<< 3456, 256, 0, stream>>>(x, qlw, qlb, kw, vw, qpw, pw,
                                            xT, qinT, wkv, pwb);
    k_kv_mfma   <<< 2816, 256, 0, stream>>>(wkv, xT, qinT,
                                            kb, kbs, kbb, vb, vbs, vbb,
                                            qpb, qbs, qbb, kbf, vT, q_t);
    k_attn      <<< 2048, 256, 0, stream>>>(q_t, kbf, vT, btab,
                                            vlw, vlb, vlbs, vlbb, attT);
    k_pconv_mfma<<<  768, 256, 0, stream>>>(attT, pwb, pb, pbs, pbb, out);
}

// Round 14
// 288.241 us; speedup vs baseline: 1.0343x; 1.0024x over previous
//
#include <hip/hip_runtime.h>
#include <hip/hip_bf16.h>

typedef __hip_bfloat16 bf16;
typedef __attribute__((ext_vector_type(8))) short short8;   // 8 bf16 (4 VGPRs)
typedef __attribute__((ext_vector_type(4))) short short4v;
typedef __attribute__((ext_vector_type(4))) float f32x4;

__device__ __forceinline__ short f2bf(float f) {            // f32 -> bf16 bits
    bf16 h = __float2bfloat16(f);
    return *reinterpret_cast<short*>(&h);
}
__device__ __forceinline__ float u2f(unsigned short u) {    // bf16 bits -> f32
    return __uint_as_float(((unsigned)u) << 16);
}
__device__ __forceinline__ unsigned cvt_pk(float lo, float hi) {
    unsigned r;                                             // 2xf32 -> 2xbf16
    asm("v_cvt_pk_bf16_f32 %0, %1, %2" : "=v"(r) : "v"(lo), "v"(hi));
    return r;
}

// Shapes: B=256, C=384, N=196 (14x14), N2=49 (7x7), HEADS=8, KD=16, D=64,
// NHKD=128, DH=512, OUT=384. Inputs fp32, output fp32.
// ws carve (143,654,912 B):
//   xT   bf16 [256][208][384]            @ 0
//   qinT bf16 [256][64][384] (alias attT)@ 40,894,464
//   attT bf16 [256][64][512]             @ 40,894,464  (rows p>=49 unused)
//   q_t  bf16 [256*8][49][16] (PRE-SCALED by 0.25)      @ 57,671,680
//   kbf  bf16 [256*8][208][16] (packed)  @ 60,882,944
//   vT   bf16 [256*8][64][208]           @ 88,145,920
//   wkv  bf16 [768][384] (k,v,qproj w)   @ 142,671,872
//   pwb  bf16 [384][512]                 @ 143,261,696

// ---------------------------------------------------------------------------
// k_prep: blocks 0..1535  = {x chunk -> LDS fp32 (f32x4 coalesced, once);
//                            emit xT bf16 transpose (short8 stores); compute
//                            q_local dwconv + pool -> qinT bf16}
//         blocks 1536..3455 = weight cvt to bf16.
__global__ __launch_bounds__(256) void k_prep(const float* __restrict__ x,
        const float* __restrict__ qlw, const float* __restrict__ qlb,
        const float* __restrict__ kw, const float* __restrict__ vw,
        const float* __restrict__ qpw, const float* __restrict__ pw,
        short* __restrict__ xT, short* __restrict__ qinT,
        short* __restrict__ wkv, short* __restrict__ pwb) {
    __shared__ float sX[64 * 197];           // 50,432 B, stride 197 (coprime)
    int bid = blockIdx.x, tid = threadIdx.x;
    if (bid < 1536) {
        int ct = bid % 6, b = bid / 6;
        // ---- load x[b][ct*64..+64][0..195] as f32x4, coalesced, once
        const float* xb = x + ((long)b * 384 + ct * 64) * 196;
        for (int i = tid; i < 64 * 49; i += 256) {
            int c = i / 49, n4 = i % 49;
            f32x4 v = *(const f32x4*)(xb + c * 196 + n4 * 4);
            float* d = sX + c * 197 + n4 * 4;
            d[0] = v[0]; d[1] = v[1]; d[2] = v[2]; d[3] = v[3];
        }
        __syncthreads();
        // ---- xT[b][n][c] = bf16(x[b][c][n]); short8 stores; rows 196..207 zero
        for (int i = tid; i < 196 * 8; i += 256) {
            int n = i >> 3, c0 = (i & 7) * 8;
            short8 o;
#pragma unroll
            for (int j = 0; j < 8; j++) o[j] = f2bf(sX[(c0 + j) * 197 + n]);
            *(short8*)(xT + ((long)b * 208 + n) * 384 + ct * 64 + c0) = o;
        }
        for (int i = tid; i < 12 * 8; i += 256) {
            int n = 196 + (i >> 3), c0 = (i & 7) * 8;
            *(short8*)(xT + ((long)b * 208 + n) * 384 + ct * 64 + c0)
                = (short8){0,0,0,0,0,0,0,0};
        }
        // ---- qinT: thread owns column c = tid%64; p walks tid/64, +4
        {
            int c = tid & 63;
            int cg = ct * 64 + c;
            const float* wc = qlw + cg * 9;
            float w9[9];
#pragma unroll
            for (int j = 0; j < 9; j++) w9[j] = wc[j];
            float bia = qlb[cg];
            const float* xr = sX + c * 197;
            for (int p = tid >> 6; p < 49; p += 4) {
                int h2 = p / 7, w2 = p % 7;
                float acc = bia;
#pragma unroll
                for (int kh = 0; kh < 3; kh++) {
                    int hin = 2 * h2 - 1 + kh;
                    if (hin < 0 || hin >= 14) continue;
#pragma unroll
                    for (int kk = 0; kk < 3; kk++) {
                        int win = 2 * w2 - 1 + kk;
                        if (win < 0 || win >= 14) continue;
                        acc += xr[hin * 14 + win] * w9[kh * 3 + kk];
                    }
                }
                acc += xr[(2 * h2) * 14 + 2 * w2];
                qinT[((long)b * 64 + p) * 384 + cg] = f2bf(acc);
            }
            for (int p = 49 + (tid >> 6); p < 64; p += 4)
                qinT[((long)b * 64 + p) * 384 + cg] = 0;
        }
    } else {
        // ---- weights -> bf16: wkv = [kw | vw | qpw], pwb = pw
        int idx = (bid - 1536) * 256 + tid;
        if (idx < 294912) {
            float v;
            if (idx < 49152) v = kw[idx];
            else if (idx < 245760) v = vw[idx - 49152];
            else v = qpw[idx - 245760];
            wkv[idx] = f2bf(v);
        } else {
            int j = idx - 294912;
            pwb[j] = f2bf(pw[j]);
        }
    }
}

// ---------------------------------------------------------------------------
// K+V+Q 1x1 convs via MFMA, XCD-grouped decode (11 sub-blocks of one b share
// the XCD L2). BK=64, 6 K-iterations, sA/sB LDS-staged with reg-prefetch
// (best-measured form, 52.2-52.4us). Wave = 2 octiles x 7 ntiles.
// kbf PACKED [bh][208][16]. q_t written PRE-SCALED by 0.25 (bit-identical:
// power-of-two scaling commutes with bf16 rounding) so k_attn stages Q as a
// plain copy.
__global__ __launch_bounds__(256, 3) void k_kv_mfma(const short* __restrict__ wkv,
        const short* __restrict__ xT, const short* __restrict__ qinT,
        const float* __restrict__ kb, const float* __restrict__ kbs,
        const float* __restrict__ kbb, const float* __restrict__ vb,
        const float* __restrict__ vbs, const float* __restrict__ vbb,
        const float* __restrict__ qpb, const float* __restrict__ qbs,
        const float* __restrict__ qbb,
        short* __restrict__ kbf, short* __restrict__ vT, short* __restrict__ q_t) {
    __shared__ short sA[128 * 72];       // w: [oc][k64]
    __shared__ short sB[112 * 72];       // x: [n-half][k64]
    int bid = blockIdx.x, tid = threadIdx.x;
    int tt = bid >> 3;
    int b = (bid & 7) * 32 + tt / 11;    // 2816 = 8 XCD * 32 b * 11 sub
    int sub = tt % 11;
    int wave = tid >> 6, lane = tid & 63, quad = lane >> 4, l15 = lane & 15;

    if (sub == 10) {
        // ---------------- Q projection: [128 oc] x [64 p] over K=384, BK=64
        f32x4 qa[2][4];
#pragma unroll
        for (int t = 0; t < 2; t++)
#pragma unroll
            for (int nt = 0; nt < 4; nt++) qa[t][nt] = (f32x4){0.f,0.f,0.f,0.f};
        for (int ct = 0; ct < 6; ct++) {
#pragma unroll
            for (int j = 0; j < 4; j++) {
                int s = tid + j * 256, r = s >> 3, c8 = s & 7;
                *(short8*)(sA + r * 72 + c8 * 8)
                    = *(const short8*)(wkv + (long)(640 + r) * 384 + ct * 64 + c8 * 8);
            }
#pragma unroll
            for (int j = 0; j < 2; j++) {
                int s = tid + j * 256, r = s >> 3, c8 = s & 7;
                *(short8*)(sB + r * 72 + c8 * 8)
                    = *(const short8*)(qinT + ((long)b * 64 + r) * 384 + ct * 64 + c8 * 8);
            }
            __syncthreads();
#pragma unroll
            for (int ks = 0; ks < 2; ks++) {
                short8 bw0 = *(const short8*)(sA + (wave * 32 + l15) * 72 + ks * 32 + quad * 8);
                short8 bw1 = *(const short8*)(sA + (wave * 32 + 16 + l15) * 72 + ks * 32 + quad * 8);
#pragma unroll
                for (int nt = 0; nt < 4; nt++) {
                    short8 ax = *(const short8*)(sB + (nt * 16 + l15) * 72 + ks * 32 + quad * 8);
                    qa[0][nt] = __builtin_amdgcn_mfma_f32_16x16x32_bf16(ax, bw0, qa[0][nt], 0, 0, 0);
                    qa[1][nt] = __builtin_amdgcn_mfma_f32_16x16x32_bf16(ax, bw1, qa[1][nt], 0, 0, 0);
                }
            }
            __syncthreads();
        }
#pragma unroll
        for (int t = 0; t < 2; t++) {
            int oc = wave * 32 + t * 16 + l15;          // 0..127
            int hh = oc >> 4, kd = oc & 15;
            float sc = qbs[oc], bi = qpb[oc], bb2 = qbb[oc];
#pragma unroll
            for (int nt = 0; nt < 4; nt++) {
#pragma unroll
                for (int r = 0; r < 4; r++) {
                    int p = nt * 16 + quad * 4 + r;
                    if (p < 49)
                        q_t[(((long)b * 8 + hh) * 49 + p) * 16 + kd]
                            = f2bf(0.25f * (sc * (qa[t][nt][r] + bi) + bb2));
                }
            }
        }
        return;
    }

    // ---------------- K/V path: block 128oc x 112n; wave = 2 octiles x 7 nt
    int ocblk = sub >> 1;                // 0..4
    int nh = sub & 1;                    // n-half: rows [nh*112, +112)
    int ocbase = ocblk * 128;
    int nbase = nh * 112;
    int nrows = nh ? 96 : 112;           // real xT rows in this half
    int obase = wave * 32;               // wave's oc offset within block

    f32x4 acc[2][7];
#pragma unroll
    for (int oct = 0; oct < 2; oct++)
#pragma unroll
        for (int j = 0; j < 7; j++) acc[oct][j] = (f32x4){0.f,0.f,0.f,0.f};

    // one-time zero of sB rows 96..111 for the short half (never re-written)
    if (nh) {
        for (int i = tid; i < 128; i += 256) {
            int row = 96 + (i >> 3), c8 = i & 7;
            *(short8*)(sB + row * 72 + c8 * 8) = (short8){0,0,0,0,0,0,0,0};
        }
    }

    short8 pA[4], pB[4], nA[4], nB[4];
    {
#pragma unroll
        for (int j = 0; j < 4; j++) {
            int s = tid + j * 256, r = s >> 3, c8 = s & 7;
            pA[j] = *(const short8*)(wkv + (long)(ocbase + r) * 384 + c8 * 8);
            if (s < nrows * 8)
                pB[j] = *(const short8*)(xT + ((long)b * 208 + nbase + r) * 384 + c8 * 8);
        }
    }

    for (int ct = 0; ct < 6; ct++) {
#pragma unroll
        for (int j = 0; j < 4; j++) {
            int s = tid + j * 256, r = s >> 3, c8 = s & 7;
            *(short8*)(sA + r * 72 + c8 * 8) = pA[j];
            if (s < nrows * 8)
                *(short8*)(sB + r * 72 + c8 * 8) = pB[j];
        }
        __syncthreads();
        if (ct < 5) {
            int cn = ct + 1;
#pragma unroll
            for (int j = 0; j < 4; j++) {
                int s = tid + j * 256, r = s >> 3, c8 = s & 7;
                nA[j] = *(const short8*)(wkv + (long)(ocbase + r) * 384 + cn * 64 + c8 * 8);
                if (s < nrows * 8)
                    nB[j] = *(const short8*)(xT + ((long)b * 208 + nbase + r) * 384 + cn * 64 + c8 * 8);
            }
        }
#pragma unroll
        for (int ks = 0; ks < 2; ks++) {
            short8 aw0 = *(const short8*)(sA + (obase + l15) * 72 + ks * 32 + quad * 8);
            short8 aw1 = *(const short8*)(sA + (obase + 16 + l15) * 72 + ks * 32 + quad * 8);
#pragma unroll
            for (int j = 0; j < 7; j++) {
                short8 bx = *(const short8*)(sB + (j * 16 + l15) * 72 + ks * 32 + quad * 8);
                acc[0][j] = __builtin_amdgcn_mfma_f32_16x16x32_bf16(bx, aw0, acc[0][j], 0, 0, 0);
                acc[1][j] = __builtin_amdgcn_mfma_f32_16x16x32_bf16(bx, aw1, acc[1][j], 0, 0, 0);
            }
        }
        __syncthreads();
#pragma unroll
        for (int j = 0; j < 4; j++) { pA[j] = nA[j]; pB[j] = nB[j]; }
    }

    // epilogue: row (quad*4+r) = n-within-tile, col (l15) = oc within octile
#pragma unroll
    for (int oct = 0; oct < 2; oct++) {
        int oc = ocbase + obase + oct * 16 + l15;
        if (ocblk == 0) {                             // K outputs, packed 16-kd
            int hh = oc >> 4, kd = oc & 15;
            float sc = kbs[oc], bi = kb[oc], bb2 = kbb[oc];
            short* kbase = kbf + ((long)(b * 8 + hh) * 208) * 16 + kd;
#pragma unroll
            for (int j = 0; j < 7; j++) {
                int nt = nh * 7 + j;
                if (nt >= 13) break;
                int n0 = nt * 16 + quad * 4;
#pragma unroll
                for (int r = 0; r < 4; r++)
                    kbase[(long)(n0 + r) * 16] = f2bf(sc * (acc[oct][j][r] + bi) + bb2);
            }
        } else {                                      // V outputs
            int cc = oc - 128, hh = cc >> 6, d = cc & 63;
            float sc = vbs[cc], bi = vb[cc], bb2 = vbb[cc];
            short* vbase = vT + ((long)(b * 8 + hh) * 64 + d) * 208;
#pragma unroll
            for (int j = 0; j < 7; j++) {
                int nt = nh * 7 + j;
                if (nt >= 13) break;
                int n0 = nt * 16 + quad * 4;
                short4v ov;
                ov.x = f2bf(sc * (acc[oct][j][0] + bi) + bb2);
                ov.y = f2bf(sc * (acc[oct][j][1] + bi) + bb2);
                ov.z = f2bf(sc * (acc[oct][j][2] + bi) + bb2);
                ov.w = f2bf(sc * (acc[oct][j][3] + bi) + bb2);
                *(short4v*)(vbase + n0) = ov;
            }
        }
    }
}

// ---------------------------------------------------------------------------
// attention per (b,h), swapped-operand QK^T with bias as MFMA C-in. Q arrives
// PRE-SCALED by 0.25 from k_kv (bit-identical fold) -> staging is a plain
// short8 copy, no VALU conversion. PV: P packed via v_cvt_pk_bf16_f32,
// transposed through sP[64][72] in FOUR 2-ks batches. LDS 38,912 B ->
// 3 blocks/CU. attT rows p>=49 not written.
__global__ __launch_bounds__(256, 3) void k_attn(const short* __restrict__ q_t,
        const short* __restrict__ kbf, const short* __restrict__ vT,
        const float* __restrict__ bias_tab,
        const float* __restrict__ vlw, const float* __restrict__ vlb,
        const float* __restrict__ vlbs, const float* __restrict__ vlbb,
        short* __restrict__ attT) {
    __shared__ short smem[19456];            // 38,912 B
    short* sQ = smem;                        // [64][40] phase A (cols 16+ zero)
    short* sK = smem + 2560;                 // [208][24] phase A
    short* sV = smem;                        // [64][232] phase B (alias A)
    short* sP = smem + 14848;                // [64][72] P batch tile
    int bh = blockIdx.x, b = bh >> 3, h = bh & 7, tid = threadIdx.x;
    int wave = tid >> 6, lane = tid & 63, quad = lane >> 4, l15 = lane & 15;
    int prow = wave * 16 + l15;

    // ---- issue Q, K, bias loads (all independent)
    const short8* qg8 = (const short8*)(q_t + (long)bh * 784);
    short8 qv[2]; int qp[2], qc[2];
#pragma unroll
    for (int j = 0; j < 2; j++) {
        int i = tid + j * 256;
        qp[j] = i / 5; qc[j] = i % 5;
        qv[j] = (short8){0,0,0,0,0,0,0,0};
        if (i < 320 && qp[j] < 49 && qc[j] < 2)
            qv[j] = qg8[qp[j] * 2 + qc[j]];          // pre-scaled: plain copy
    }
    const short8* kg8 = (const short8*)(kbf + (long)bh * 3328);
    short8 kv[2];
#pragma unroll
    for (int j = 0; j < 2; j++) {
        int i = tid + j * 256;
        if (i < 416) kv[j] = kg8[i];
    }
    int pb = prow < 49 ? prow : 48;
    const float* bp = bias_tab + ((long)(h * 49 + pb) * 196 + quad * 4);
    f32x4 bi[13];
#pragma unroll
    for (int nt = 0; nt < 13; nt++) bi[nt] = *(const f32x4*)(bp + nt * 16);

    // ---- stage Q, K
#pragma unroll
    for (int j = 0; j < 2; j++) {
        int i = tid + j * 256;
        if (i < 320) *(short8*)(sQ + qp[j] * 40 + qc[j] * 8) = qv[j];
    }
#pragma unroll
    for (int j = 0; j < 2; j++) {
        int i = tid + j * 256;
        if (i < 416) *(short8*)(sK + (i >> 1) * 24 + (i & 1) * 8) = kv[j];
    }
    __syncthreads();

    // ---- QK^T swapped, C-in = bias: lane holds S[p=prow][n=nt*16+quad*4+r]
    f32x4 s2[13];
    short8 aQ = *(const short8*)(sQ + prow * 40 + quad * 8);
#pragma unroll
    for (int nt = 0; nt < 13; nt++) {
        short8 bK = (short8){0,0,0,0,0,0,0,0};
        if (quad < 2) bK = *(const short8*)(sK + (nt * 16 + l15) * 24 + quad * 8);
        s2[nt] = __builtin_amdgcn_mfma_f32_16x16x32_bf16(bK, aQ, bi[nt], 0, 0, 0);
    }
    __syncthreads();        // sQ/sK dead; region becomes sV

    // ---- mask n>=196 (nt=12, quad*4+r >= 4)
#pragma unroll
    for (int r = 0; r < 4; r++)
        if (quad * 4 + r >= 4) s2[12][r] = -1e30f;

    // ---- issue V loads (land during softmax)
    const short* vg = vT + (long)bh * 13312;
    short8 vv[7]; int vd[7], vc[7];
#pragma unroll
    for (int j = 0; j < 7; j++) {
        int i = tid + j * 256;
        vd[j] = i / 26; vc[j] = i % 26;
        if (i < 1664) vv[j] = *(const short8*)(vg + i * 8);
    }

    // ---- softmax over the lane-resident row
    float m = -3e38f;
#pragma unroll
    for (int nt = 0; nt < 13; nt++)
        m = fmaxf(m, fmaxf(fmaxf(s2[nt][0], s2[nt][1]), fmaxf(s2[nt][2], s2[nt][3])));
    m = fmaxf(m, __shfl_xor(m, 16));
    m = fmaxf(m, __shfl_xor(m, 32));
    float sum = 0.f;
#pragma unroll
    for (int nt = 0; nt < 13; nt++) {
#pragma unroll
        for (int r = 0; r < 4; r++) {
            float e = __expf(s2[nt][r] - m);
            s2[nt][r] = e; sum += e;
        }
    }
    sum += __shfl_xor(sum, 16);
    sum += __shfl_xor(sum, 32);
    float inv = 1.f / sum;

    // ---- stage V (+ zero pad cols 208..223)
#pragma unroll
    for (int j = 0; j < 7; j++) {
        int i = tid + j * 256;
        if (i < 1664) *(short8*)(sV + vd[j] * 232 + vc[j] * 8) = vv[j];
    }
    {
        int d = tid >> 2, c0 = 208 + (tid & 3) * 4;
        *(short4v*)(sV + d * 232 + c0) = (short4v){0,0,0,0};
    }
    __syncthreads();        // sV visible to all waves

    // ---- PV: four 2-ks batches; P packed with cvt_pk, transposed via sP.
    //      sP stride 72 shorts = 144B (bank-start 4*l15 -> 2-way = free).
    //      Per-wave rows only; DS in-order per wave => no barriers.
    f32x4 o[4];
#pragma unroll
    for (int dt = 0; dt < 4; dt++) o[dt] = (f32x4){0.f,0.f,0.f,0.f};
#pragma unroll
    for (int bb = 0; bb < 4; bb++) {
#pragma unroll
        for (int ntl = 0; ntl < 4; ntl++) {
            int nt = bb * 4 + ntl;
            uint2 w;
            if (nt < 13) {
                w.x = cvt_pk(s2[nt][0] * inv, s2[nt][1] * inv);
                w.y = cvt_pk(s2[nt][2] * inv, s2[nt][3] * inv);
            } else w = (uint2){0u, 0u};
            *(uint2*)(sP + prow * 72 + ntl * 16 + quad * 4) = w;
        }
#pragma unroll
        for (int ksl = 0; ksl < 2; ksl++) {
            int ks = bb * 2 + ksl;
            if (ks > 6) break;
            short8 aP = *(const short8*)(sP + prow * 72 + ksl * 32 + quad * 8);
#pragma unroll
            for (int dt = 0; dt < 4; dt++) {
                short8 bV = *(const short8*)(sV + (dt * 16 + l15) * 232 + ks * 32 + quad * 8);
                o[dt] = __builtin_amdgcn_mfma_f32_16x16x32_bf16(aP, bV, o[dt], 0, 0, 0);
            }
        }
    }

    // ---- epilogue: v_local 9-tap from sV + BN + ReLU -> attT (p<49 only)
#pragma unroll
    for (int r = 0; r < 4; r++) {
        int p = wave * 16 + quad * 4 + r;
        if (p >= 49) continue;
        int h2 = p / 7, w2 = p % 7;
#pragma unroll
        for (int dt = 0; dt < 4; dt++) {
            int d = dt * 16 + l15, c = h * 64 + d;
            float acc2 = vlb[c];
            const float* wc = vlw + c * 9;
            const short* vrow = sV + d * 232;
#pragma unroll
            for (int kh = 0; kh < 3; kh++) {
                int hin = 2 * h2 - 1 + kh;
                if (hin < 0 || hin >= 14) continue;
#pragma unroll
                for (int kk = 0; kk < 3; kk++) {
                    int win = 2 * w2 - 1 + kk;
                    if (win < 0 || win >= 14) continue;
                    acc2 += u2f((unsigned short)vrow[hin * 14 + win]) * wc[kh * 3 + kk];
                }
            }
            float vl = vlbs[c] * acc2 + vlbb[c];
            attT[((long)b * 64 + p) * 512 + h * 64 + d]
                = f2bf(fmaxf(o[dt][r] + vl, 0.f));
        }
    }
}

// ---------------------------------------------------------------------------
// out = bn(conv1x1(relu(att))) via MFMA. XCD-grouped decode: 3 ocblks of one
// b share the attT slab via the same XCD's L2. Pad rows 49..63 of sB zeroed
// once; per-ct staging covers rows 0..48 only.
__global__ __launch_bounds__(256, 4) void k_pconv_mfma(const short* __restrict__ attT,
        const short* __restrict__ pwb, const float* __restrict__ bias,
        const float* __restrict__ bns, const float* __restrict__ bnb,
        float* __restrict__ out) {
    __shared__ short sA[128 * 72];
    __shared__ short sB[64 * 72];
    int bid = blockIdx.x, tid = threadIdx.x;
    int tt = bid >> 3;
    int b = (bid & 7) * 32 + tt / 3;     // 768 = 8 XCD * 32 b * 3 ocblk
    int ocblk = tt % 3;
    int wave = tid >> 6, lane = tid & 63, quad = lane >> 4, l15 = lane & 15;
    int ocbase = ocblk * 128;

    // zero sB rows 49..63 once (static across all ct)
    for (int i = tid; i < 15 * 8; i += 256) {
        int r = 49 + i / 8, c8 = i % 8;
        *(short8*)(sB + r * 72 + c8 * 8) = (short8){0,0,0,0,0,0,0,0};
    }

    f32x4 acc[2][4];
#pragma unroll
    for (int t = 0; t < 2; t++)
#pragma unroll
        for (int nt = 0; nt < 4; nt++) acc[t][nt] = (f32x4){0.f,0.f,0.f,0.f};

    for (int ct = 0; ct < 8; ct++) {
        for (int i = tid; i < 1024; i += 256) {
            int r = i >> 3, c8 = i & 7;
            *(short8*)(sA + r * 72 + c8 * 8)
                = *(const short8*)(pwb + (long)(ocbase + r) * 512 + ct * 64 + c8 * 8);
        }
        for (int i = tid; i < 392; i += 256) {       // rows 0..48 only
            int r = i >> 3, c8 = i & 7;
            *(short8*)(sB + r * 72 + c8 * 8)
                = *(const short8*)(attT + ((long)b * 64 + r) * 512 + ct * 64 + c8 * 8);
        }
        __syncthreads();
        short8 a00 = *(const short8*)(sA + (wave * 32 + l15) * 72 + quad * 8);
        short8 a01 = *(const short8*)(sA + (wave * 32 + l15) * 72 + 32 + quad * 8);
        short8 a10 = *(const short8*)(sA + (wave * 32 + 16 + l15) * 72 + quad * 8);
        short8 a11 = *(const short8*)(sA + (wave * 32 + 16 + l15) * 72 + 32 + quad * 8);
#pragma unroll
        for (int nt = 0; nt < 4; nt++) {
            short8 b0 = *(const short8*)(sB + (nt * 16 + l15) * 72 + quad * 8);
            short8 b1 = *(const short8*)(sB + (nt * 16 + l15) * 72 + 32 + quad * 8);
            acc[0][nt] = __builtin_amdgcn_mfma_f32_16x16x32_bf16(a00, b0, acc[0][nt], 0, 0, 0);
            acc[0][nt] = __builtin_amdgcn_mfma_f32_16x16x32_bf16(a01, b1, acc[0][nt], 0, 0, 0);
            acc[1][nt] = __builtin_amdgcn_mfma_f32_16x16x32_bf16(a10, b0, acc[1][nt], 0, 0, 0);
            acc[1][nt] = __builtin_amdgcn_mfma_f32_16x16x32_bf16(a11, b1, acc[1][nt], 0, 0, 0);
        }
        __syncthreads();
    }

#pragma unroll
    for (int t = 0; t < 2; t++) {
#pragma unroll
        for (int nt = 0; nt < 4; nt++) {
            int p = nt * 16 + l15;
            if (p >= 49) continue;
#pragma unroll
            for (int r = 0; r < 4; r++) {
                int oc = ocbase + wave * 32 + t * 16 + quad * 4 + r;
                out[((long)b * 384 + oc) * 49 + p]
                    = bns[oc] * (acc[t][nt][r] + bias[oc]) + bnb[oc];
            }
        }
    }
}

// ---------------------------------------------------------------------------
extern "C" void kernel_launch(void* const* d_in, const int* in_sizes, int n_in,
                              void* d_out, int out_size, void* d_ws, size_t ws_size,
                              hipStream_t stream) {
    const float* x    = (const float*)d_in[0];
    const float* qlw  = (const float*)d_in[1];
    const float* qlb  = (const float*)d_in[2];
    const float* qpw  = (const float*)d_in[3];
    const float* qpb  = (const float*)d_in[4];
    const float* qbs  = (const float*)d_in[5];
    const float* qbb  = (const float*)d_in[6];
    const float* kw   = (const float*)d_in[7];
    const float* kb   = (const float*)d_in[8];
    const float* kbs  = (const float*)d_in[9];
    const float* kbb  = (const float*)d_in[10];
    const float* vw   = (const float*)d_in[11];
    const float* vb   = (const float*)d_in[12];
    const float* vbs  = (const float*)d_in[13];
    const float* vbb  = (const float*)d_in[14];
    const float* vlw  = (const float*)d_in[15];
    const float* vlb  = (const float*)d_in[16];
    const float* vlbs = (const float*)d_in[17];
    const float* vlbb = (const float*)d_in[18];
    const float* btab = (const float*)d_in[19];
    const float* pw   = (const float*)d_in[20];
    const float* pb   = (const float*)d_in[21];
    const float* pbs  = (const float*)d_in[22];
    const float* pbb  = (const float*)d_in[23];
    float* out = (float*)d_out;

    char* W = (char*)d_ws;
    short* xT   = (short*)(W + 0);
    short* qinT = (short*)(W + 40894464);     // aliased by attT
    short* attT = (short*)(W + 40894464);
    short* q_t  = (short*)(W + 57671680);     // pre-scaled by 0.25
    short* kbf  = (short*)(W + 60882944);     // packed [2048][208][16]
    short* vT   = (short*)(W + 88145920);
    short* wkv  = (short*)(W + 142671872);
    short* pwb  = (short*)(W + 143261696);    // end 143,654,912
    if (ws_size < 143654912) return;

    k_prep      <<< 3456, 256, 0, stream>>>(x, qlw, qlb, kw, vw, qpw, pw,
                                            xT, qinT, wkv, pwb);
    k_kv_mfma   <<< 2816, 256, 0, stream>>>(wkv, xT, qinT,
                                            kb, kbs, kbb, vb, vbs, vbb,
                                            qpb, qbs, qbb, kbf, vT, q_t);
    k_attn      <<< 2048, 256, 0, stream>>>(q_t, kbf, vT, btab,
                                            vlw, vlb, vlbs, vlbb, attT);
    k_pconv_mfma<<<  768, 256, 0, stream>>>(attT, pwb, pb, pbs, pbb, out);
}